// Round 1
// baseline (2718.500 us; speedup 1.0000x reference)
//
#include <hip/hip_runtime.h>
#include <hip/hip_bf16.h>
#include <cstdint>

#define HSZ    4194304ull   // B*H*S*Dh floats per head tensor
#define S_LEN  1024
#define NHEAD  16
#define DH     64

// ======================= projection GEMM =======================
// q_proj/k_proj/v_proj = x @ [wq;wk;wv]^T + bias, written directly into
// per-head layout [B,H,S,Dh] (5 tensors: q1,q2,k1,k2,v), unroped.
__global__ __launch_bounds__(256) void proj_gemm_kernel(
    const float* __restrict__ X,
    const float* __restrict__ wq, const float* __restrict__ wk, const float* __restrict__ wv,
    const float* __restrict__ bq, const float* __restrict__ bk, const float* __restrict__ bv,
    float* __restrict__ heads)
{
    __shared__ float As[16][128];
    __shared__ float Bs[16][128];
    const int t  = threadIdx.x;
    const int tx = t & 15, ty = t >> 4;
    const int m0 = blockIdx.y * 128;
    const int n0 = blockIdx.x * 128;

    const float* W; const float* bias; int nloc;
    if (n0 < 2048)      { W = wq; bias = bq; nloc = n0; }
    else if (n0 < 4096) { W = wk; bias = bk; nloc = n0 - 2048; }
    else                { W = wv; bias = bv; nloc = n0 - 4096; }

    float acc[8][8];
#pragma unroll
    for (int i = 0; i < 8; ++i)
#pragma unroll
        for (int j = 0; j < 8; ++j) acc[i][j] = 0.f;

    const int r  = t >> 2;
    const int c4 = (t & 3) * 4;

    for (int k0 = 0; k0 < 1024; k0 += 16) {
        float4 a0 = *(const float4*)&X[(size_t)(m0 + r)      * 1024 + k0 + c4];
        float4 a1 = *(const float4*)&X[(size_t)(m0 + r + 64) * 1024 + k0 + c4];
        float4 b0 = *(const float4*)&W[(size_t)(nloc + r)      * 1024 + k0 + c4];
        float4 b1 = *(const float4*)&W[(size_t)(nloc + r + 64) * 1024 + k0 + c4];
        __syncthreads();
        As[c4+0][r]    = a0.x; As[c4+1][r]    = a0.y; As[c4+2][r]    = a0.z; As[c4+3][r]    = a0.w;
        As[c4+0][r+64] = a1.x; As[c4+1][r+64] = a1.y; As[c4+2][r+64] = a1.z; As[c4+3][r+64] = a1.w;
        Bs[c4+0][r]    = b0.x; Bs[c4+1][r]    = b0.y; Bs[c4+2][r]    = b0.z; Bs[c4+3][r]    = b0.w;
        Bs[c4+0][r+64] = b1.x; Bs[c4+1][r+64] = b1.y; Bs[c4+2][r+64] = b1.z; Bs[c4+3][r+64] = b1.w;
        __syncthreads();
#pragma unroll
        for (int kk = 0; kk < 16; ++kk) {
            float4 alo = *(float4*)&As[kk][ty*8];
            float4 ahi = *(float4*)&As[kk][ty*8+4];
            float4 blo = *(float4*)&Bs[kk][tx*8];
            float4 bhi = *(float4*)&Bs[kk][tx*8+4];
            float av[8]  = {alo.x, alo.y, alo.z, alo.w, ahi.x, ahi.y, ahi.z, ahi.w};
            float bfr[8] = {blo.x, blo.y, blo.z, blo.w, bhi.x, bhi.y, bhi.z, bhi.w};
#pragma unroll
            for (int i = 0; i < 8; ++i)
#pragma unroll
                for (int j = 0; j < 8; ++j)
                    acc[i][j] = fmaf(av[i], bfr[j], acc[i][j]);
        }
    }

    // epilogue: scatter into [B,H,S,Dh] per-head layout
    const int cn0    = n0 & 1023;   // col within tensor (tile never crosses a tensor boundary)
    const int tensor = n0 >> 10;    // 0:q1 1:q2 2:k1 3:k2 4:v
    float* dstT = heads + (size_t)tensor * HSZ;
#pragma unroll
    for (int j4 = 0; j4 < 2; ++j4) {
        const int ncol = cn0 + tx*8 + j4*4;
        const int head = ncol >> 6;
        const int d    = ncol & 63;
        float4 bb = *(const float4*)&bias[nloc + tx*8 + j4*4];
#pragma unroll
        for (int i = 0; i < 8; ++i) {
            const int m = m0 + ty*8 + i;
            const int b = m >> 10, s = m & 1023;
            float4 o;
            o.x = acc[i][j4*4+0] + bb.x;
            o.y = acc[i][j4*4+1] + bb.y;
            o.z = acc[i][j4*4+2] + bb.z;
            o.w = acc[i][j4*4+3] + bb.w;
            *(float4*)&dstT[(((size_t)(b*NHEAD + head)) * S_LEN + s) * DH + d] = o;
        }
    }
}

// ======================= RoPE (in place) =======================
// tensors 0..3 (q1,q2,k1,k2); one thread owns pair (j, j+32) of one row.
__global__ __launch_bounds__(256) void rope_kernel(float* __restrict__ heads)
{
    const int idx = blockIdx.x * 256 + threadIdx.x;   // 4 * 65536 * 32 = 8388608
    const int tensor = idx >> 21;
    const int rem = idx & 2097151;
    const int row = rem >> 5;           // (b*16+h)*1024 + s
    const int j   = rem & 31;
    const int s   = row & 1023;
    float* base = heads + (size_t)tensor * HSZ + (size_t)row * DH;
    const float x1 = base[j];
    const float x2 = base[j + 32];
    const float freq = 1.0f / powf(10000.0f, (float)(2 * j) * (1.0f / 64.0f));
    const float ang  = (float)s * freq;
    float sn, cs;
    sincosf(ang, &sn, &cs);
    base[j]      = x1 * cs - x2 * sn;
    base[j + 32] = x1 * sn + x2 * cs;
}

// ======================= attention =======================
// One block = one (b,h) and 8 query rows. For p in {a1, a2}:
//   scores -> softmax -> write a_p -> sc := C * a_p * (p ? -lambda : 1)
//   ctx += sc @ V   (linearity of the diff through the PV matmul)
__global__ __launch_bounds__(256) void attn_kernel(
    const float* __restrict__ heads,
    const float* __restrict__ Cmask, const int* __restrict__ pad,
    const float* __restrict__ lam_p,
    float* __restrict__ out_a1, float* __restrict__ out_a2,
    float* __restrict__ merged)
{
    __shared__ float sc[8][1024];     // 32 KB
    __shared__ float kst[64][65];     // 16.6 KB (padded: bank-conflict-free)
    __shared__ float qt_s[8][64];     // 2 KB

    const int t  = threadIdx.x;
    const int bh = blockIdx.y;
    const int b  = bh >> 4;
    const int h  = bh & 15;
    const int q0 = blockIdx.x * 8;
    const float lam = lam_p[0];

    const float* q1 = heads + (size_t)bh * (S_LEN * DH);
    const float* q2 = q1 + HSZ;
    const float* k1 = q1 + 2 * HSZ;
    const float* k2 = q1 + 3 * HSZ;
    const float* vv = q1 + 4 * HSZ;

    const int d_ = t & 63;      // lane dim / key index
    const int rp = t >> 6;      // row-pair id (0..3)

    float accA = 0.f, accB = 0.f;   // ctx for rows 2rp, 2rp+1 at dim d_

    for (int p = 0; p < 2; ++p) {
        const float* Q = p ? q2 : q1;
        const float* K = p ? k2 : k1;
        __syncthreads();
        // stage 8 query rows
        {
            int i0 = t;
            qt_s[i0 >> 6][i0 & 63] = Q[(size_t)(q0 + (i0 >> 6)) * DH + (i0 & 63)];
            int i1 = t + 256;
            qt_s[i1 >> 6][i1 & 63] = Q[(size_t)(q0 + (i1 >> 6)) * DH + (i1 & 63)];
        }
        // ---- scores ----
        for (int kt = 0; kt < 16; ++kt) {
            const int k0 = kt * 64;
            __syncthreads();
#pragma unroll
            for (int i = 0; i < 4; ++i) {       // stage K tile 64x64
                int idx = t + i * 256;
                int row = idx >> 4, cc = (idx & 15) * 4;
                float4 f = *(const float4*)&K[(size_t)(k0 + row) * DH + cc];
                kst[row][cc+0] = f.x; kst[row][cc+1] = f.y; kst[row][cc+2] = f.z; kst[row][cc+3] = f.w;
            }
            __syncthreads();
            const int kk = d_;
            float s0 = 0.f, s1 = 0.f;
#pragma unroll
            for (int d4 = 0; d4 < 16; ++d4) {
                float4 qa = *(float4*)&qt_s[2*rp][d4*4];
                float4 qb = *(float4*)&qt_s[2*rp+1][d4*4];
                float k0v = kst[kk][d4*4+0], k1v = kst[kk][d4*4+1];
                float k2v = kst[kk][d4*4+2], k3v = kst[kk][d4*4+3];
                s0 = fmaf(qa.x, k0v, fmaf(qa.y, k1v, fmaf(qa.z, k2v, fmaf(qa.w, k3v, s0))));
                s1 = fmaf(qb.x, k0v, fmaf(qb.y, k1v, fmaf(qb.z, k2v, fmaf(qb.w, k3v, s1))));
            }
            s0 *= 0.125f; s1 *= 0.125f;          // 1/sqrt(64)
            if (pad[b * S_LEN + k0 + kk] == 0) { s0 = -1e9f; s1 = -1e9f; }
            sc[2*rp][k0+kk]   = s0;
            sc[2*rp+1][k0+kk] = s1;
        }
        __syncthreads();
        // ---- softmax + write a_p + build combined ----
        {
            const int row = t >> 5, c = t & 31;
            float mx = -3.4e38f;
#pragma unroll
            for (int j = 0; j < 32; ++j) mx = fmaxf(mx, sc[row][c + 32*j]);
#pragma unroll
            for (int off = 16; off > 0; off >>= 1) mx = fmaxf(mx, __shfl_xor(mx, off));
            float sum = 0.f;
#pragma unroll
            for (int j = 0; j < 32; ++j) {
                float e = expf(sc[row][c + 32*j] - mx);
                sc[row][c + 32*j] = e;
                sum += e;
            }
#pragma unroll
            for (int off = 16; off > 0; off >>= 1) sum += __shfl_xor(sum, off);
            const float inv = 1.0f / sum;
            const float fac = p ? -lam : 1.0f;
            float* aout = (p ? out_a2 : out_a1) + ((size_t)bh * S_LEN + q0 + row) * S_LEN;
            const float* Crow = Cmask + (size_t)(q0 + row) * S_LEN;
#pragma unroll
            for (int j = 0; j < 32; ++j) {
                const int col = c + 32*j;
                float a = sc[row][col] * inv;
                aout[col] = a;
                sc[row][col] = Crow[col] * a * fac;
            }
        }
        __syncthreads();
        // ---- ctx accumulation: ctx += sc @ V ----
        for (int kt = 0; kt < 16; ++kt) {
            const int k0 = kt * 64;
#pragma unroll
            for (int i = 0; i < 4; ++i) {       // stage V tile 64x64
                int idx = t + i * 256;
                int row = idx >> 4, cc = (idx & 15) * 4;
                float4 f = *(const float4*)&vv[(size_t)(k0 + row) * DH + cc];
                kst[row][cc+0] = f.x; kst[row][cc+1] = f.y; kst[row][cc+2] = f.z; kst[row][cc+3] = f.w;
            }
            __syncthreads();
#pragma unroll
            for (int k4 = 0; k4 < 16; ++k4) {
                float4 ca = *(float4*)&sc[2*rp][k0 + k4*4];
                float4 cb = *(float4*)&sc[2*rp+1][k0 + k4*4];
                float v0 = kst[k4*4+0][d_], v1 = kst[k4*4+1][d_];
                float v2 = kst[k4*4+2][d_], v3 = kst[k4*4+3][d_];
                accA = fmaf(ca.x, v0, fmaf(ca.y, v1, fmaf(ca.z, v2, fmaf(ca.w, v3, accA))));
                accB = fmaf(cb.x, v0, fmaf(cb.y, v1, fmaf(cb.z, v2, fmaf(cb.w, v3, accB))));
            }
            __syncthreads();
        }
    }
    merged[((size_t)(b * S_LEN) + q0 + 2*rp)     * 1024 + h * DH + d_] = accA;
    merged[((size_t)(b * S_LEN) + q0 + 2*rp + 1) * 1024 + h * DH + d_] = accB;
}

// ======================= group-norm stats =======================
__global__ __launch_bounds__(256) void stats_kernel(
    const float* __restrict__ merged, float* __restrict__ stats)
{
    const int g = blockIdx.x;           // b*16 + h
    const int b = g >> 4, h = g & 15;
    const int t = threadIdx.x;
    float sum = 0.f, sq = 0.f;
    for (int i = t; i < 65536; i += 256) {
        const int s = i >> 6, d = i & 63;
        const float v = merged[((size_t)(b * S_LEN + s)) * 1024 + h * DH + d];
        sum += v; sq += v * v;
    }
#pragma unroll
    for (int off = 32; off > 0; off >>= 1) {
        sum += __shfl_xor(sum, off);
        sq  += __shfl_xor(sq, off);
    }
    __shared__ float rs[4], rq[4];
    const int wid = t >> 6;
    if ((t & 63) == 0) { rs[wid] = sum; rq[wid] = sq; }
    __syncthreads();
    if (t == 0) {
        const float S = rs[0] + rs[1] + rs[2] + rs[3];
        const float Q = rq[0] + rq[1] + rq[2] + rq[3];
        const float mean = S * (1.0f / 65536.0f);
        const float var  = Q * (1.0f / 65536.0f) - mean * mean;
        stats[2*g]   = mean;
        stats[2*g+1] = rsqrtf(var + 1e-5f);
    }
}

// ======================= output GEMM =======================
// out = ((normed * gn_w + gn_b) * 0.2) @ out_w^T + out_b, norm fused at A-load
__global__ __launch_bounds__(256) void out_gemm_kernel(
    const float* __restrict__ merged, const float* __restrict__ Wo, const float* __restrict__ bo,
    const float* __restrict__ gw, const float* __restrict__ gb,
    const float* __restrict__ stats, float* __restrict__ out)
{
    __shared__ float As[16][128];
    __shared__ float Bs[16][128];
    const int t  = threadIdx.x;
    const int tx = t & 15, ty = t >> 4;
    const int m0 = blockIdx.y * 128;
    const int n0 = blockIdx.x * 128;
    const int b  = m0 >> 10;

    float acc[8][8];
#pragma unroll
    for (int i = 0; i < 8; ++i)
#pragma unroll
        for (int j = 0; j < 8; ++j) acc[i][j] = 0.f;

    const int r  = t >> 2;
    const int c4 = (t & 3) * 4;

    for (int k0 = 0; k0 < 1024; k0 += 16) {
        const int hh = k0 >> 6;                          // k-tile stays inside one head
        const float mean = stats[2 * (b * NHEAD + hh)];
        const float inv  = stats[2 * (b * NHEAD + hh) + 1];
        float4 gw4 = *(const float4*)&gw[k0 + c4];
        float4 gb4 = *(const float4*)&gb[k0 + c4];
        float4 a0 = *(const float4*)&merged[(size_t)(m0 + r)      * 1024 + k0 + c4];
        float4 a1 = *(const float4*)&merged[(size_t)(m0 + r + 64) * 1024 + k0 + c4];
        float4 b0 = *(const float4*)&Wo[(size_t)(n0 + r)      * 1024 + k0 + c4];
        float4 b1 = *(const float4*)&Wo[(size_t)(n0 + r + 64) * 1024 + k0 + c4];
        a0.x = ((a0.x - mean) * inv * gw4.x + gb4.x) * 0.2f;
        a0.y = ((a0.y - mean) * inv * gw4.y + gb4.y) * 0.2f;
        a0.z = ((a0.z - mean) * inv * gw4.z + gb4.z) * 0.2f;
        a0.w = ((a0.w - mean) * inv * gw4.w + gb4.w) * 0.2f;
        a1.x = ((a1.x - mean) * inv * gw4.x + gb4.x) * 0.2f;
        a1.y = ((a1.y - mean) * inv * gw4.y + gb4.y) * 0.2f;
        a1.z = ((a1.z - mean) * inv * gw4.z + gb4.z) * 0.2f;
        a1.w = ((a1.w - mean) * inv * gw4.w + gb4.w) * 0.2f;
        __syncthreads();
        As[c4+0][r]    = a0.x; As[c4+1][r]    = a0.y; As[c4+2][r]    = a0.z; As[c4+3][r]    = a0.w;
        As[c4+0][r+64] = a1.x; As[c4+1][r+64] = a1.y; As[c4+2][r+64] = a1.z; As[c4+3][r+64] = a1.w;
        Bs[c4+0][r]    = b0.x; Bs[c4+1][r]    = b0.y; Bs[c4+2][r]    = b0.z; Bs[c4+3][r]    = b0.w;
        Bs[c4+0][r+64] = b1.x; Bs[c4+1][r+64] = b1.y; Bs[c4+2][r+64] = b1.z; Bs[c4+3][r+64] = b1.w;
        __syncthreads();
#pragma unroll
        for (int kk = 0; kk < 16; ++kk) {
            float4 alo = *(float4*)&As[kk][ty*8];
            float4 ahi = *(float4*)&As[kk][ty*8+4];
            float4 blo = *(float4*)&Bs[kk][tx*8];
            float4 bhi = *(float4*)&Bs[kk][tx*8+4];
            float av[8]  = {alo.x, alo.y, alo.z, alo.w, ahi.x, ahi.y, ahi.z, ahi.w};
            float bfr[8] = {blo.x, blo.y, blo.z, blo.w, bhi.x, bhi.y, bhi.z, bhi.w};
#pragma unroll
            for (int i = 0; i < 8; ++i)
#pragma unroll
                for (int j = 0; j < 8; ++j)
                    acc[i][j] = fmaf(av[i], bfr[j], acc[i][j]);
        }
    }

#pragma unroll
    for (int j4 = 0; j4 < 2; ++j4) {
        const int n = n0 + tx*8 + j4*4;
        float4 bb = *(const float4*)&bo[n];
#pragma unroll
        for (int i = 0; i < 8; ++i) {
            const int m = m0 + ty*8 + i;
            float4 o;
            o.x = acc[i][j4*4+0] + bb.x;
            o.y = acc[i][j4*4+1] + bb.y;
            o.z = acc[i][j4*4+2] + bb.z;
            o.w = acc[i][j4*4+3] + bb.w;
            *(float4*)&out[(size_t)m * 1024 + n] = o;
        }
    }
}

// ======================= launcher =======================
extern "C" void kernel_launch(void* const* d_in, const int* in_sizes, int n_in,
                              void* d_out, int out_size, void* d_ws, size_t ws_size,
                              hipStream_t stream)
{
    const float* x   = (const float*)d_in[0];
    const float* lam = (const float*)d_in[1];
    const float* C   = (const float*)d_in[2];
    const int*   pad = (const int*)  d_in[3];
    const float* wq  = (const float*)d_in[4];
    const float* bq  = (const float*)d_in[5];
    const float* wk  = (const float*)d_in[6];
    const float* bk  = (const float*)d_in[7];
    const float* wv  = (const float*)d_in[8];
    const float* bv  = (const float*)d_in[9];
    const float* wo  = (const float*)d_in[10];
    const float* bo  = (const float*)d_in[11];
    const float* gw  = (const float*)d_in[12];
    const float* gb  = (const float*)d_in[13];

    float* out = (float*)d_out;
    float* a1  = out + 4194304;          // [B,H,S,S]
    float* a2  = a1 + 67108864;

    float* ws     = (float*)d_ws;
    float* heads  = ws;                   // 5 * HSZ floats (q1,q2,k1,k2,v)
    float* merged = ws + 5 * HSZ;         // B*S*D floats
    float* stats  = merged + HSZ;         // 128 floats

    proj_gemm_kernel<<<dim3(40, 32), 256, 0, stream>>>(x, wq, wk, wv, bq, bk, bv, heads);
    rope_kernel<<<32768, 256, 0, stream>>>(heads);
    attn_kernel<<<dim3(128, 64), 256, 0, stream>>>(heads, C, pad, lam, a1, a2, merged);
    stats_kernel<<<64, 256, 0, stream>>>(merged, stats);
    out_gemm_kernel<<<dim3(8, 32), 256, 0, stream>>>(merged, wo, bo, gw, gb, stats, out);
}

// Round 2
// 1200.969 us; speedup vs baseline: 2.2636x; 2.2636x over previous
//
#include <hip/hip_runtime.h>
#include <hip/hip_bf16.h>
#include <hip/hip_fp16.h>
#include <cstdint>

#define HSZ    4194304ull   // B*H*S*Dh elements per head tensor
#define S_LEN  1024
#define NHEAD  16
#define DH     64

typedef __attribute__((ext_vector_type(8))) short bf16x8;
typedef __attribute__((ext_vector_type(8))) unsigned short u16x8;
typedef __attribute__((ext_vector_type(4))) float f32x4;
#define MFMA(a,b,c) __builtin_amdgcn_mfma_f32_16x16x32_bf16(a,b,c,0,0,0)

__device__ __forceinline__ unsigned short f2bf(float f) {
    union { float f; uint32_t u; } v; v.f = f;
    uint32_t r = (v.u + 0x7fffu + ((v.u >> 16) & 1u)) >> 16;
    return (unsigned short)r;
}
__device__ __forceinline__ float bf2f(unsigned short u) {
    union { uint32_t u; float f; } v; v.u = (uint32_t)u << 16;
    return v.f;
}
__device__ __forceinline__ unsigned short f2h(float f) { return __half_as_ushort(__float2half(f)); }
__device__ __forceinline__ float h2f(unsigned short u) { return __half2float(__ushort_as_half(u)); }

// ======================= projection GEMM (fp32, unchanged) =======================
__global__ __launch_bounds__(256) void proj_gemm_kernel(
    const float* __restrict__ X,
    const float* __restrict__ wq, const float* __restrict__ wk, const float* __restrict__ wv,
    const float* __restrict__ bq, const float* __restrict__ bk, const float* __restrict__ bv,
    float* __restrict__ heads)
{
    __shared__ float As[16][128];
    __shared__ float Bs[16][128];
    const int t  = threadIdx.x;
    const int tx = t & 15, ty = t >> 4;
    const int m0 = blockIdx.y * 128;
    const int n0 = blockIdx.x * 128;

    const float* W; const float* bias; int nloc;
    if (n0 < 2048)      { W = wq; bias = bq; nloc = n0; }
    else if (n0 < 4096) { W = wk; bias = bk; nloc = n0 - 2048; }
    else                { W = wv; bias = bv; nloc = n0 - 4096; }

    float acc[8][8];
#pragma unroll
    for (int i = 0; i < 8; ++i)
#pragma unroll
        for (int j = 0; j < 8; ++j) acc[i][j] = 0.f;

    const int r  = t >> 2;
    const int c4 = (t & 3) * 4;

    for (int k0 = 0; k0 < 1024; k0 += 16) {
        float4 a0 = *(const float4*)&X[(size_t)(m0 + r)      * 1024 + k0 + c4];
        float4 a1 = *(const float4*)&X[(size_t)(m0 + r + 64) * 1024 + k0 + c4];
        float4 b0 = *(const float4*)&W[(size_t)(nloc + r)      * 1024 + k0 + c4];
        float4 b1 = *(const float4*)&W[(size_t)(nloc + r + 64) * 1024 + k0 + c4];
        __syncthreads();
        As[c4+0][r]    = a0.x; As[c4+1][r]    = a0.y; As[c4+2][r]    = a0.z; As[c4+3][r]    = a0.w;
        As[c4+0][r+64] = a1.x; As[c4+1][r+64] = a1.y; As[c4+2][r+64] = a1.z; As[c4+3][r+64] = a1.w;
        Bs[c4+0][r]    = b0.x; Bs[c4+1][r]    = b0.y; Bs[c4+2][r]    = b0.z; Bs[c4+3][r]    = b0.w;
        Bs[c4+0][r+64] = b1.x; Bs[c4+1][r+64] = b1.y; Bs[c4+2][r+64] = b1.z; Bs[c4+3][r+64] = b1.w;
        __syncthreads();
#pragma unroll
        for (int kk = 0; kk < 16; ++kk) {
            float4 alo = *(float4*)&As[kk][ty*8];
            float4 ahi = *(float4*)&As[kk][ty*8+4];
            float4 blo = *(float4*)&Bs[kk][tx*8];
            float4 bhi = *(float4*)&Bs[kk][tx*8+4];
            float av[8]  = {alo.x, alo.y, alo.z, alo.w, ahi.x, ahi.y, ahi.z, ahi.w};
            float bfr[8] = {blo.x, blo.y, blo.z, blo.w, bhi.x, bhi.y, bhi.z, bhi.w};
#pragma unroll
            for (int i = 0; i < 8; ++i)
#pragma unroll
                for (int j = 0; j < 8; ++j)
                    acc[i][j] = fmaf(av[i], bfr[j], acc[i][j]);
        }
    }

    const int cn0    = n0 & 1023;
    const int tensor = n0 >> 10;    // 0:q1 1:q2 2:k1 3:k2 4:v
    float* dstT = heads + (size_t)tensor * HSZ;
#pragma unroll
    for (int j4 = 0; j4 < 2; ++j4) {
        const int ncol = cn0 + tx*8 + j4*4;
        const int head = ncol >> 6;
        const int d    = ncol & 63;
        float4 bb = *(const float4*)&bias[nloc + tx*8 + j4*4];
#pragma unroll
        for (int i = 0; i < 8; ++i) {
            const int m = m0 + ty*8 + i;
            const int b = m >> 10, s = m & 1023;
            float4 o;
            o.x = acc[i][j4*4+0] + bb.x;
            o.y = acc[i][j4*4+1] + bb.y;
            o.z = acc[i][j4*4+2] + bb.z;
            o.w = acc[i][j4*4+3] + bb.w;
            *(float4*)&dstT[(((size_t)(b*NHEAD + head)) * S_LEN + s) * DH + d] = o;
        }
    }
}

// ======================= RoPE + bf16 hi/lo split =======================
// reads fp32 q1,q2,k1,k2 heads; writes 8 bf16 tensors: q1h,q1l,q2h,q2l,k1h,k1l,k2h,k2l
__global__ __launch_bounds__(256) void rope_conv_kernel(
    const float* __restrict__ heads, unsigned short* __restrict__ qk)
{
    const int idx = blockIdx.x * 256 + threadIdx.x;   // 4 * 65536 * 32
    const int tensor = idx >> 21;
    const int rem = idx & 2097151;
    const int row = rem >> 5;           // (b*16+h)*1024 + s
    const int j   = rem & 31;
    const int s   = row & 1023;
    const float* base = heads + (size_t)tensor * HSZ + (size_t)row * DH;
    const float x1 = base[j];
    const float x2 = base[j + 32];
    const float freq = 1.0f / powf(10000.0f, (float)(2 * j) * (1.0f / 64.0f));
    const float ang  = (float)s * freq;
    float sn, cs;
    sincosf(ang, &sn, &cs);
    const float r1 = x1 * cs - x2 * sn;
    const float r2 = x1 * sn + x2 * cs;

    unsigned short* hi = qk + (size_t)(tensor * 2)     * HSZ + (size_t)row * DH;
    unsigned short* lo = qk + (size_t)(tensor * 2 + 1) * HSZ + (size_t)row * DH;
    const unsigned short h1 = f2bf(r1);
    const unsigned short h2 = f2bf(r2);
    hi[j]      = h1;
    hi[j + 32] = h2;
    lo[j]      = f2bf(r1 - bf2f(h1));
    lo[j + 32] = f2bf(r2 - bf2f(h2));
}

// ======================= V transpose + bf16 convert =======================
// v fp32 [bh][s][64] -> vt bf16 [bh][64][s]
__global__ __launch_bounds__(256) void vt_conv_kernel(
    const float* __restrict__ vsrc, unsigned short* __restrict__ vt)
{
    __shared__ float tile[64][65];
    const int t  = threadIdx.x;
    const int bh = blockIdx.y;
    const int s0 = blockIdx.x * 64;
    const int row = t >> 2, q = t & 3;
    const float* src = vsrc + ((size_t)bh * S_LEN + s0 + row) * DH + q * 16;
#pragma unroll
    for (int k = 0; k < 4; ++k) {
        float4 f = *(const float4*)&src[k * 4];
        tile[row][q*16 + k*4 + 0] = f.x;
        tile[row][q*16 + k*4 + 1] = f.y;
        tile[row][q*16 + k*4 + 2] = f.z;
        tile[row][q*16 + k*4 + 3] = f.w;
    }
    __syncthreads();
    const int d = row;
    unsigned short* dst = vt + ((size_t)bh * DH + d) * S_LEN + s0 + q * 16;
#pragma unroll
    for (int half = 0; half < 2; ++half) {
        u16x8 o;
#pragma unroll
        for (int k = 0; k < 8; ++k) o[k] = f2bf(tile[q*16 + half*8 + k][d]);
        *(u16x8*)&dst[half * 8] = o;
    }
}

// ======================= attention (MFMA) =======================
// block = 512 thr (8 waves), Q-tile 32 rows, one (b,h).
// per pass p: scores (hi/lo split, 3 mfma) -> f16 LDS -> softmax (2 sweeps)
// -> a_p out + combined bf16 written into the SAME LDS slots -> PV mfma accumulate.
__global__ __launch_bounds__(512, 4) void attn_kernel(
    const unsigned short* __restrict__ qk,   // 8 tensors [bh][1024][64]
    const unsigned short* __restrict__ vt,   // [bh][64][1024]
    const float* __restrict__ Cm, const int* __restrict__ pad,
    const float* __restrict__ lam_p,
    float* __restrict__ out_a1, float* __restrict__ out_a2,
    float* __restrict__ merged)
{
    __shared__ __align__(16) unsigned short sc[32][1032];
    __shared__ float rowstat[32][2];

    const int t  = threadIdx.x;
    const int w  = t >> 6;
    const int l  = t & 63;
    const int ln = l & 15;
    const int kf = (l >> 4) * 8;
    const int bh = blockIdx.y, b = bh >> 4, h = bh & 15;
    const int q0 = blockIdx.x * 32;
    const float lam = lam_p[0];

    const f32x4 Z = {0.f, 0.f, 0.f, 0.f};
    f32x4 c40 = Z, c41 = Z;    // ctx accumulators (rt0, rt1), persist across passes

    const int dt  = w & 3;
    const int khf = (w >> 2) * 16;

    for (int p = 0; p < 2; ++p) {
        const unsigned short* Qh = qk + (size_t)(2*p)     * HSZ + (size_t)bh * 65536;
        const unsigned short* Ql = qk + (size_t)(2*p + 1) * HSZ + (size_t)bh * 65536;
        const unsigned short* Kh = qk + (size_t)(4 + 2*p) * HSZ + (size_t)bh * 65536;
        const unsigned short* Kl = qk + (size_t)(5 + 2*p) * HSZ + (size_t)bh * 65536;

        const size_t qb0 = (size_t)(q0 + ln) * 64 + kf;
        const size_t qb1 = (size_t)(q0 + 16 + ln) * 64 + kf;
        bf16x8 qh00 = *(const bf16x8*)(Qh + qb0);
        bf16x8 qh01 = *(const bf16x8*)(Qh + qb0 + 32);
        bf16x8 ql00 = *(const bf16x8*)(Ql + qb0);
        bf16x8 ql01 = *(const bf16x8*)(Ql + qb0 + 32);
        bf16x8 qh10 = *(const bf16x8*)(Qh + qb1);
        bf16x8 qh11 = *(const bf16x8*)(Qh + qb1 + 32);
        bf16x8 ql10 = *(const bf16x8*)(Ql + qb1);
        bf16x8 ql11 = *(const bf16x8*)(Ql + qb1 + 32);

        __syncthreads();   // sc reuse vs previous pass's PV reads

        // ---- scores: each wave covers 8 coltiles (16 keys each), both row-tiles ----
#pragma unroll 2
        for (int j = 0; j < 8; ++j) {
            const int ct = w * 8 + j;
            const int key = ct * 16 + ln;
            const size_t kb = (size_t)key * 64 + kf;
            bf16x8 kh0 = *(const bf16x8*)(Kh + kb);
            bf16x8 kh1 = *(const bf16x8*)(Kh + kb + 32);
            bf16x8 kl0 = *(const bf16x8*)(Kl + kb);
            bf16x8 kl1 = *(const bf16x8*)(Kl + kb + 32);
            f32x4 s0 = Z, s1 = Z;
            s0 = MFMA(qh00, kh0, s0); s0 = MFMA(qh01, kh1, s0);
            s1 = MFMA(qh10, kh0, s1); s1 = MFMA(qh11, kh1, s1);
            s0 = MFMA(qh00, kl0, s0); s0 = MFMA(qh01, kl1, s0);
            s1 = MFMA(qh10, kl0, s1); s1 = MFMA(qh11, kl1, s1);
            s0 = MFMA(ql00, kh0, s0); s0 = MFMA(ql01, kh1, s0);
            s1 = MFMA(ql10, kh0, s1); s1 = MFMA(ql11, kh1, s1);
            const int pv = pad[b * S_LEN + key];
            const float mm = (pv == 0) ? 0.0f : 0.125f;
            const float ma = (pv == 0) ? -60000.0f : 0.0f;
#pragma unroll
            for (int r = 0; r < 4; ++r) {
                sc[(l >> 4) * 4 + r][key]      = f2h(s0[r] * mm + ma);
                sc[16 + (l >> 4) * 4 + r][key] = f2h(s1[r] * mm + ma);
            }
        }
        __syncthreads();

        // ---- softmax sweep 1: per-row max & sum (wave per row, 4 rows/wave) ----
#pragma unroll
        for (int rr = 0; rr < 4; ++rr) {
            const int row = w * 4 + rr;
            u16x8 v0 = *(const u16x8*)&sc[row][l * 8];
            u16x8 v1 = *(const u16x8*)&sc[row][l * 8 + 512];
            float x[16];
#pragma unroll
            for (int i = 0; i < 8; ++i) { x[i] = h2f(v0[i]); x[8 + i] = h2f(v1[i]); }
            float mx = x[0];
#pragma unroll
            for (int i = 1; i < 16; ++i) mx = fmaxf(mx, x[i]);
#pragma unroll
            for (int o = 1; o < 64; o <<= 1) mx = fmaxf(mx, __shfl_xor(mx, o));
            float sm = 0.f;
#pragma unroll
            for (int i = 0; i < 16; ++i) sm += __expf(x[i] - mx);
#pragma unroll
            for (int o = 1; o < 64; o <<= 1) sm += __shfl_xor(sm, o);
            if (l == 0) { rowstat[row][0] = mx; rowstat[row][1] = 1.0f / sm; }
        }
        __syncthreads();

        // ---- softmax sweep 2: write a_p, overwrite sc slots with bf16 combined ----
        {
            const int row = t >> 4, ci = t & 15;
            const float mx  = rowstat[row][0];
            const float inv = rowstat[row][1];
            const float fac = p ? -lam : 1.0f;
            float* aout = (p ? out_a2 : out_a1) + ((size_t)bh * S_LEN + q0 + row) * S_LEN;
            const float* Crow = Cm + (size_t)(q0 + row) * S_LEN;
#pragma unroll
            for (int it = 0; it < 8; ++it) {
                const int c0 = ci * 8 + it * 128;
                u16x8 sv = *(const u16x8*)&sc[row][c0];
                float4 Ca = *(const float4*)&Crow[c0];
                float4 Cb = *(const float4*)&Crow[c0 + 4];
                float e[8];
#pragma unroll
                for (int i = 0; i < 8; ++i) e[i] = __expf(h2f(sv[i]) - mx) * inv;
                float4 oa = {e[0], e[1], e[2], e[3]};
                float4 ob = {e[4], e[5], e[6], e[7]};
                *(float4*)&aout[c0]     = oa;
                *(float4*)&aout[c0 + 4] = ob;
                u16x8 cw;
                cw[0] = f2bf(Ca.x * e[0] * fac);
                cw[1] = f2bf(Ca.y * e[1] * fac);
                cw[2] = f2bf(Ca.z * e[2] * fac);
                cw[3] = f2bf(Ca.w * e[3] * fac);
                cw[4] = f2bf(Cb.x * e[4] * fac);
                cw[5] = f2bf(Cb.y * e[5] * fac);
                cw[6] = f2bf(Cb.z * e[6] * fac);
                cw[7] = f2bf(Cb.w * e[7] * fac);
                *(u16x8*)&sc[row][c0] = cw;
            }
        }
        __syncthreads();

        // ---- PV: ctx += combined @ V ; wave = (dt, k-half) ----
        {
            const unsigned short* vtb = vt + (size_t)bh * 65536
                                           + (size_t)(dt * 16 + ln) * S_LEN + kf;
#pragma unroll 4
            for (int ks = khf; ks < khf + 16; ++ks) {
                bf16x8 A0 = *(const bf16x8*)&sc[ln][ks * 32 + kf];
                bf16x8 A1 = *(const bf16x8*)&sc[16 + ln][ks * 32 + kf];
                bf16x8 Bv = *(const bf16x8*)(vtb + ks * 32);
                c40 = MFMA(A0, Bv, c40);
                c41 = MFMA(A1, Bv, c41);
            }
        }
    }

    // ---- cross k-half reduction + store merged ----
    __syncthreads();
    float* red = (float*)&sc[0][0];
    if ((w >> 2) == 1) {
        *(f32x4*)&red[((dt * 2 + 0) * 64 + l) * 4] = c40;
        *(f32x4*)&red[((dt * 2 + 1) * 64 + l) * 4] = c41;
    }
    __syncthreads();
    if ((w >> 2) == 0) {
        f32x4 r0 = *(const f32x4*)&red[((dt * 2 + 0) * 64 + l) * 4];
        f32x4 r1 = *(const f32x4*)&red[((dt * 2 + 1) * 64 + l) * 4];
        c40 += r0;
        c41 += r1;
        const int col = h * DH + dt * 16 + ln;
#pragma unroll
        for (int r = 0; r < 4; ++r) {
            merged[(size_t)(b * S_LEN + q0 + (l >> 4) * 4 + r) * 1024 + col]      = c40[r];
            merged[(size_t)(b * S_LEN + q0 + 16 + (l >> 4) * 4 + r) * 1024 + col] = c41[r];
        }
    }
}

// ======================= group-norm stats (unchanged) =======================
__global__ __launch_bounds__(256) void stats_kernel(
    const float* __restrict__ merged, float* __restrict__ stats)
{
    const int g = blockIdx.x;
    const int b = g >> 4, h = g & 15;
    const int t = threadIdx.x;
    float sum = 0.f, sq = 0.f;
    for (int i = t; i < 65536; i += 256) {
        const int s = i >> 6, d = i & 63;
        const float v = merged[((size_t)(b * S_LEN + s)) * 1024 + h * DH + d];
        sum += v; sq += v * v;
    }
#pragma unroll
    for (int off = 32; off > 0; off >>= 1) {
        sum += __shfl_xor(sum, off);
        sq  += __shfl_xor(sq, off);
    }
    __shared__ float rs[4], rq[4];
    const int wid = t >> 6;
    if ((t & 63) == 0) { rs[wid] = sum; rq[wid] = sq; }
    __syncthreads();
    if (t == 0) {
        const float S = rs[0] + rs[1] + rs[2] + rs[3];
        const float Q = rq[0] + rq[1] + rq[2] + rq[3];
        const float mean = S * (1.0f / 65536.0f);
        const float var  = Q * (1.0f / 65536.0f) - mean * mean;
        stats[2*g]   = mean;
        stats[2*g+1] = rsqrtf(var + 1e-5f);
    }
}

// ======================= output GEMM (fp32, unchanged) =======================
__global__ __launch_bounds__(256) void out_gemm_kernel(
    const float* __restrict__ merged, const float* __restrict__ Wo, const float* __restrict__ bo,
    const float* __restrict__ gw, const float* __restrict__ gb,
    const float* __restrict__ stats, float* __restrict__ out)
{
    __shared__ float As[16][128];
    __shared__ float Bs[16][128];
    const int t  = threadIdx.x;
    const int tx = t & 15, ty = t >> 4;
    const int m0 = blockIdx.y * 128;
    const int n0 = blockIdx.x * 128;
    const int b  = m0 >> 10;

    float acc[8][8];
#pragma unroll
    for (int i = 0; i < 8; ++i)
#pragma unroll
        for (int j = 0; j < 8; ++j) acc[i][j] = 0.f;

    const int r  = t >> 2;
    const int c4 = (t & 3) * 4;

    for (int k0 = 0; k0 < 1024; k0 += 16) {
        const int hh = k0 >> 6;
        const float mean = stats[2 * (b * NHEAD + hh)];
        const float inv  = stats[2 * (b * NHEAD + hh) + 1];
        float4 gw4 = *(const float4*)&gw[k0 + c4];
        float4 gb4 = *(const float4*)&gb[k0 + c4];
        float4 a0 = *(const float4*)&merged[(size_t)(m0 + r)      * 1024 + k0 + c4];
        float4 a1 = *(const float4*)&merged[(size_t)(m0 + r + 64) * 1024 + k0 + c4];
        float4 b0 = *(const float4*)&Wo[(size_t)(n0 + r)      * 1024 + k0 + c4];
        float4 b1 = *(const float4*)&Wo[(size_t)(n0 + r + 64) * 1024 + k0 + c4];
        a0.x = ((a0.x - mean) * inv * gw4.x + gb4.x) * 0.2f;
        a0.y = ((a0.y - mean) * inv * gw4.y + gb4.y) * 0.2f;
        a0.z = ((a0.z - mean) * inv * gw4.z + gb4.z) * 0.2f;
        a0.w = ((a0.w - mean) * inv * gw4.w + gb4.w) * 0.2f;
        a1.x = ((a1.x - mean) * inv * gw4.x + gb4.x) * 0.2f;
        a1.y = ((a1.y - mean) * inv * gw4.y + gb4.y) * 0.2f;
        a1.z = ((a1.z - mean) * inv * gw4.z + gb4.z) * 0.2f;
        a1.w = ((a1.w - mean) * inv * gw4.w + gb4.w) * 0.2f;
        __syncthreads();
        As[c4+0][r]    = a0.x; As[c4+1][r]    = a0.y; As[c4+2][r]    = a0.z; As[c4+3][r]    = a0.w;
        As[c4+0][r+64] = a1.x; As[c4+1][r+64] = a1.y; As[c4+2][r+64] = a1.z; As[c4+3][r+64] = a1.w;
        Bs[c4+0][r]    = b0.x; Bs[c4+1][r]    = b0.y; Bs[c4+2][r]    = b0.z; Bs[c4+3][r]    = b0.w;
        Bs[c4+0][r+64] = b1.x; Bs[c4+1][r+64] = b1.y; Bs[c4+2][r+64] = b1.z; Bs[c4+3][r+64] = b1.w;
        __syncthreads();
#pragma unroll
        for (int kk = 0; kk < 16; ++kk) {
            float4 alo = *(float4*)&As[kk][ty*8];
            float4 ahi = *(float4*)&As[kk][ty*8+4];
            float4 blo = *(float4*)&Bs[kk][tx*8];
            float4 bhi = *(float4*)&Bs[kk][tx*8+4];
            float av[8]  = {alo.x, alo.y, alo.z, alo.w, ahi.x, ahi.y, ahi.z, ahi.w};
            float bfr[8] = {blo.x, blo.y, blo.z, blo.w, bhi.x, bhi.y, bhi.z, bhi.w};
#pragma unroll
            for (int i = 0; i < 8; ++i)
#pragma unroll
                for (int j = 0; j < 8; ++j)
                    acc[i][j] = fmaf(av[i], bfr[j], acc[i][j]);
        }
    }

#pragma unroll
    for (int j4 = 0; j4 < 2; ++j4) {
        const int n = n0 + tx*8 + j4*4;
        float4 bb = *(const float4*)&bo[n];
#pragma unroll
        for (int i = 0; i < 8; ++i) {
            const int m = m0 + ty*8 + i;
            float4 o;
            o.x = acc[i][j4*4+0] + bb.x;
            o.y = acc[i][j4*4+1] + bb.y;
            o.z = acc[i][j4*4+2] + bb.z;
            o.w = acc[i][j4*4+3] + bb.w;
            *(float4*)&out[(size_t)m * 1024 + n] = o;
        }
    }
}

// ======================= launcher =======================
extern "C" void kernel_launch(void* const* d_in, const int* in_sizes, int n_in,
                              void* d_out, int out_size, void* d_ws, size_t ws_size,
                              hipStream_t stream)
{
    const float* x   = (const float*)d_in[0];
    const float* lam = (const float*)d_in[1];
    const float* C   = (const float*)d_in[2];
    const int*   pad = (const int*)  d_in[3];
    const float* wq  = (const float*)d_in[4];
    const float* bq  = (const float*)d_in[5];
    const float* wk  = (const float*)d_in[6];
    const float* bk  = (const float*)d_in[7];
    const float* wv  = (const float*)d_in[8];
    const float* bv  = (const float*)d_in[9];
    const float* wo  = (const float*)d_in[10];
    const float* bo  = (const float*)d_in[11];
    const float* gw  = (const float*)d_in[12];
    const float* gb  = (const float*)d_in[13];

    float* out = (float*)d_out;
    float* a1  = out + 4194304;
    float* a2  = a1 + 67108864;

    float* ws     = (float*)d_ws;
    float* heads  = ws;                        // 5*HSZ fp32 (q1,q2,k1,k2,v)
    float* merged = ws + 5 * HSZ;              // HSZ fp32
    float* stats  = merged + HSZ;              // 128 fp32
    unsigned short* qk = (unsigned short*)(stats + 128);   // 8*HSZ bf16
    unsigned short* vt = qk + 8 * HSZ;                     // HSZ bf16

    proj_gemm_kernel<<<dim3(40, 32), 256, 0, stream>>>(x, wq, wk, wv, bq, bk, bv, heads);
    rope_conv_kernel<<<32768, 256, 0, stream>>>(heads, qk);
    vt_conv_kernel<<<dim3(16, 64), 256, 0, stream>>>(heads + 4 * HSZ, vt);
    attn_kernel<<<dim3(32, 64), 512, 0, stream>>>(qk, vt, C, pad, lam, a1, a2, merged);
    stats_kernel<<<64, 256, 0, stream>>>(merged, stats);
    out_gemm_kernel<<<dim3(8, 32), 256, 0, stream>>>(merged, wo, bo, gw, gb, stats, out);
}

// Round 3
// 722.429 us; speedup vs baseline: 3.7630x; 1.6624x over previous
//
#include <hip/hip_runtime.h>
#include <hip/hip_bf16.h>
#include <hip/hip_fp16.h>
#include <cstdint>

#define HSZ    4194304ull   // B*H*S*Dh elements per head tensor
#define S_LEN  1024
#define NHEAD  16
#define DH     64

typedef __attribute__((ext_vector_type(8))) short bf16x8;
typedef __attribute__((ext_vector_type(8))) unsigned short u16x8;
typedef __attribute__((ext_vector_type(4))) unsigned short u16x4;
typedef __attribute__((ext_vector_type(4))) float f32x4;
#define MFMA(a,b,c) __builtin_amdgcn_mfma_f32_16x16x32_bf16(a,b,c,0,0,0)

__device__ __forceinline__ unsigned short f2bf(float f) {
    union { float f; uint32_t u; } v; v.f = f;
    uint32_t r = (v.u + 0x7fffu + ((v.u >> 16) & 1u)) >> 16;
    return (unsigned short)r;
}
__device__ __forceinline__ float bf2f(unsigned short u) {
    union { uint32_t u; float f; } v; v.u = (uint32_t)u << 16;
    return v.f;
}
__device__ __forceinline__ unsigned short f2h(float f) { return __half_as_ushort(__float2half(f)); }
__device__ __forceinline__ float h2f(unsigned short u) { return __half2float(__ushort_as_half(u)); }

// ======================= conv: X fp32 -> bf16 hi/lo =======================
__global__ __launch_bounds__(256) void conv_x_kernel(
    const float* __restrict__ X, unsigned short* __restrict__ xh, unsigned short* __restrict__ xl)
{
    const int idx = blockIdx.x * 256 + threadIdx.x;     // 524288
    float4 a = *(const float4*)&X[idx * 8];
    float4 b = *(const float4*)&X[idx * 8 + 4];
    float v[8] = {a.x, a.y, a.z, a.w, b.x, b.y, b.z, b.w};
    u16x8 hi, lo;
#pragma unroll
    for (int j = 0; j < 8; ++j) {
        unsigned short h = f2bf(v[j]);
        hi[j] = h;
        lo[j] = f2bf(v[j] - bf2f(h));
    }
    *(u16x8*)&xh[idx * 8] = hi;
    *(u16x8*)&xl[idx * 8] = lo;
}

// ======================= conv: weights fp32 -> bf16 (concat) =======================
// Wcat rows: [0,2048) wq, [2048,4096) wk, [4096,5120) wv, [5120,6144) wo
__global__ __launch_bounds__(256) void conv_w_kernel(
    const float* __restrict__ wq, const float* __restrict__ wk,
    const float* __restrict__ wv, const float* __restrict__ wo,
    unsigned short* __restrict__ Wcat)
{
    const int idx = blockIdx.x * 256 + threadIdx.x;     // 786432
    const int row = idx >> 7;
    const int cg  = idx & 127;
    const float* src;
    int rl;
    if (row < 2048)      { src = wq; rl = row; }
    else if (row < 4096) { src = wk; rl = row - 2048; }
    else if (row < 5120) { src = wv; rl = row - 4096; }
    else                 { src = wo; rl = row - 5120; }
    float4 a = *(const float4*)&src[(size_t)rl * 1024 + cg * 8];
    float4 b = *(const float4*)&src[(size_t)rl * 1024 + cg * 8 + 4];
    float v[8] = {a.x, a.y, a.z, a.w, b.x, b.y, b.z, b.w};
    u16x8 o;
#pragma unroll
    for (int j = 0; j < 8; ++j) o[j] = f2bf(v[j]);
    *(u16x8*)&Wcat[(size_t)row * 1024 + cg * 8] = o;
}

// ======================= projection GEMM (MFMA, hi/lo A) =======================
// C[m][n] = sum_k X[m][k] * Wcat[n][k], m in [0,4096), n in [0,5120)
// q/k results -> fp32 heads (tensors 0..3); v -> bf16 vt (transposed)
__global__ __launch_bounds__(256) void proj_mfma_kernel(
    const unsigned short* __restrict__ xh, const unsigned short* __restrict__ xl,
    const unsigned short* __restrict__ Wcat,
    const float* __restrict__ bq, const float* __restrict__ bk, const float* __restrict__ bv,
    float* __restrict__ heads, unsigned short* __restrict__ vt)
{
    __shared__ __align__(16) unsigned short Ah[128 * 64];
    __shared__ __align__(16) unsigned short Al[128 * 64];
    __shared__ __align__(16) unsigned short Bs[128 * 64];

    const int t   = threadIdx.x;
    const int bid = blockIdx.x;                 // 1280
    const int swz = (bid & 7) * 160 + (bid >> 3);
    const int n_idx = swz % 40, m_idx = swz / 40;
    const int m0 = m_idx * 128, n0 = n_idx * 128;
    const int w = t >> 6, l = t & 63, ln = l & 15, kg = l >> 4;
    const int wm = w >> 1, wn = w & 1;

    f32x4 acc[4][4];
#pragma unroll
    for (int i = 0; i < 4; ++i)
#pragma unroll
        for (int j = 0; j < 4; ++j) acc[i][j] = (f32x4){0.f, 0.f, 0.f, 0.f};

    for (int k0 = 0; k0 < 1024; k0 += 64) {
        __syncthreads();
#pragma unroll
        for (int i = 0; i < 4; ++i) {
            const int e   = t + i * 256;
            const int row = e >> 3, cg = e & 7;
            const int off = (row * 128 + cg * 16) ^ ((row & 7) << 4);
            const size_t ga = (size_t)(m0 + row) * 1024 + k0 + cg * 8;
            const size_t gb = (size_t)(n0 + row) * 1024 + k0 + cg * 8;
            *(bf16x8*)((char*)Ah + off) = *(const bf16x8*)(xh + ga);
            *(bf16x8*)((char*)Al + off) = *(const bf16x8*)(xl + ga);
            *(bf16x8*)((char*)Bs + off) = *(const bf16x8*)(Wcat + gb);
        }
        __syncthreads();
#pragma unroll
        for (int ks = 0; ks < 2; ++ks) {
            bf16x8 bfrag[4];
#pragma unroll
            for (int nj = 0; nj < 4; ++nj) {
                const int row = wn * 64 + nj * 16 + ln;
                const int off = (row * 128 + ks * 64 + kg * 16) ^ ((row & 7) << 4);
                bfrag[nj] = *(const bf16x8*)((const char*)Bs + off);
            }
#pragma unroll
            for (int mi = 0; mi < 4; ++mi) {
                const int row = wm * 64 + mi * 16 + ln;
                const int off = (row * 128 + ks * 64 + kg * 16) ^ ((row & 7) << 4);
                bf16x8 ah = *(const bf16x8*)((const char*)Ah + off);
                bf16x8 al = *(const bf16x8*)((const char*)Al + off);
#pragma unroll
                for (int nj = 0; nj < 4; ++nj) {
                    acc[mi][nj] = MFMA(ah, bfrag[nj], acc[mi][nj]);
                    acc[mi][nj] = MFMA(al, bfrag[nj], acc[mi][nj]);
                }
            }
        }
    }

    // epilogue: n0 block lies entirely in one segment (q/k/v)
    const int seg = (n0 < 2048) ? 0 : (n0 < 4096 ? 1 : 2);
#pragma unroll
    for (int mi = 0; mi < 4; ++mi) {
#pragma unroll
        for (int nj = 0; nj < 4; ++nj) {
            const int n = n0 + wn * 64 + nj * 16 + ln;
            const int mb = m0 + wm * 64 + mi * 16 + kg * 4;
            if (seg < 2) {
                const int nl = n - seg * 2048;
                const float bb = (seg == 0 ? bq : bk)[nl];
                const int tensor = seg * 2 + (nl >> 10);
                const int head = (nl >> 6) & 15, d = nl & 63;
                float* dst = heads + (size_t)tensor * HSZ;
#pragma unroll
                for (int r = 0; r < 4; ++r) {
                    const int m = mb + r, b = m >> 10, s = m & 1023;
                    dst[(((size_t)(b * 16 + head)) * 1024 + s) * 64 + d] = acc[mi][nj][r] + bb;
                }
            } else {
                const int nl = n - 4096;
                const float bb = bv[nl];
                const int head = nl >> 6, d = nl & 63;
                const int b = mb >> 10, sb = mb & 1023;
                u16x4 o;
#pragma unroll
                for (int r = 0; r < 4; ++r) o[r] = f2bf(acc[mi][nj][r] + bb);
                *(u16x4*)(vt + ((size_t)(b * 16 + head) * 64 + d) * 1024 + sb) = o;
            }
        }
    }
}

// ======================= RoPE + bf16 hi/lo split =======================
__global__ __launch_bounds__(256) void rope_conv_kernel(
    const float* __restrict__ heads, unsigned short* __restrict__ qk)
{
    const int idx = blockIdx.x * 256 + threadIdx.x;   // 4 * 65536 * 32
    const int tensor = idx >> 21;
    const int rem = idx & 2097151;
    const int row = rem >> 5;           // (b*16+h)*1024 + s
    const int j   = rem & 31;
    const int s   = row & 1023;
    const float* base = heads + (size_t)tensor * HSZ + (size_t)row * DH;
    const float x1 = base[j];
    const float x2 = base[j + 32];
    const float freq = exp2f((float)j * (-13.287712379549449f / 32.0f));
    const float ang  = (float)s * freq;
    float sn, cs;
    sincosf(ang, &sn, &cs);
    const float r1 = x1 * cs - x2 * sn;
    const float r2 = x1 * sn + x2 * cs;

    unsigned short* hi = qk + (size_t)(tensor * 2)     * HSZ + (size_t)row * DH;
    unsigned short* lo = qk + (size_t)(tensor * 2 + 1) * HSZ + (size_t)row * DH;
    const unsigned short h1 = f2bf(r1);
    const unsigned short h2 = f2bf(r2);
    hi[j]      = h1;
    hi[j + 32] = h2;
    lo[j]      = f2bf(r1 - bf2f(h1));
    lo[j + 32] = f2bf(r2 - bf2f(h2));
}

// ======================= attention (MFMA) =======================
__global__ __launch_bounds__(512, 4) void attn_kernel(
    const unsigned short* __restrict__ qk,   // 8 tensors [bh][1024][64]
    const unsigned short* __restrict__ vt,   // [bh][64][1024]
    const float* __restrict__ Cm, const int* __restrict__ pad,
    const float* __restrict__ lam_p,
    float* __restrict__ out_a1, float* __restrict__ out_a2,
    float* __restrict__ merged)
{
    __shared__ __align__(16) unsigned short sc[32][1032];
    __shared__ float rowstat[32][2];

    const int t  = threadIdx.x;
    const int w  = t >> 6;
    const int l  = t & 63;
    const int ln = l & 15;
    const int kf = (l >> 4) * 8;
    const int bh = blockIdx.y, b = bh >> 4, h = bh & 15;
    const int q0 = blockIdx.x * 32;
    const float lam = lam_p[0];

    const f32x4 Z = {0.f, 0.f, 0.f, 0.f};
    f32x4 c40 = Z, c41 = Z;

    const int dt  = w & 3;
    const int khf = (w >> 2) * 16;

    for (int p = 0; p < 2; ++p) {
        const unsigned short* Qh = qk + (size_t)(2*p)     * HSZ + (size_t)bh * 65536;
        const unsigned short* Ql = qk + (size_t)(2*p + 1) * HSZ + (size_t)bh * 65536;
        const unsigned short* Kh = qk + (size_t)(4 + 2*p) * HSZ + (size_t)bh * 65536;
        const unsigned short* Kl = qk + (size_t)(5 + 2*p) * HSZ + (size_t)bh * 65536;

        const size_t qb0 = (size_t)(q0 + ln) * 64 + kf;
        const size_t qb1 = (size_t)(q0 + 16 + ln) * 64 + kf;
        bf16x8 qh00 = *(const bf16x8*)(Qh + qb0);
        bf16x8 qh01 = *(const bf16x8*)(Qh + qb0 + 32);
        bf16x8 ql00 = *(const bf16x8*)(Ql + qb0);
        bf16x8 ql01 = *(const bf16x8*)(Ql + qb0 + 32);
        bf16x8 qh10 = *(const bf16x8*)(Qh + qb1);
        bf16x8 qh11 = *(const bf16x8*)(Qh + qb1 + 32);
        bf16x8 ql10 = *(const bf16x8*)(Ql + qb1);
        bf16x8 ql11 = *(const bf16x8*)(Ql + qb1 + 32);

        __syncthreads();

#pragma unroll 2
        for (int j = 0; j < 8; ++j) {
            const int ct = w * 8 + j;
            const int key = ct * 16 + ln;
            const size_t kb = (size_t)key * 64 + kf;
            bf16x8 kh0 = *(const bf16x8*)(Kh + kb);
            bf16x8 kh1 = *(const bf16x8*)(Kh + kb + 32);
            bf16x8 kl0 = *(const bf16x8*)(Kl + kb);
            bf16x8 kl1 = *(const bf16x8*)(Kl + kb + 32);
            f32x4 s0 = Z, s1 = Z;
            s0 = MFMA(qh00, kh0, s0); s0 = MFMA(qh01, kh1, s0);
            s1 = MFMA(qh10, kh0, s1); s1 = MFMA(qh11, kh1, s1);
            s0 = MFMA(qh00, kl0, s0); s0 = MFMA(qh01, kl1, s0);
            s1 = MFMA(qh10, kl0, s1); s1 = MFMA(qh11, kl1, s1);
            s0 = MFMA(ql00, kh0, s0); s0 = MFMA(ql01, kh1, s0);
            s1 = MFMA(ql10, kh0, s1); s1 = MFMA(ql11, kh1, s1);
            const int pv = pad[b * S_LEN + key];
            const float mm = (pv == 0) ? 0.0f : 0.125f;
            const float ma = (pv == 0) ? -60000.0f : 0.0f;
#pragma unroll
            for (int r = 0; r < 4; ++r) {
                sc[(l >> 4) * 4 + r][key]      = f2h(s0[r] * mm + ma);
                sc[16 + (l >> 4) * 4 + r][key] = f2h(s1[r] * mm + ma);
            }
        }
        __syncthreads();

#pragma unroll
        for (int rr = 0; rr < 4; ++rr) {
            const int row = w * 4 + rr;
            u16x8 v0 = *(const u16x8*)&sc[row][l * 8];
            u16x8 v1 = *(const u16x8*)&sc[row][l * 8 + 512];
            float x[16];
#pragma unroll
            for (int i = 0; i < 8; ++i) { x[i] = h2f(v0[i]); x[8 + i] = h2f(v1[i]); }
            float mx = x[0];
#pragma unroll
            for (int i = 1; i < 16; ++i) mx = fmaxf(mx, x[i]);
#pragma unroll
            for (int o = 1; o < 64; o <<= 1) mx = fmaxf(mx, __shfl_xor(mx, o));
            float sm = 0.f;
#pragma unroll
            for (int i = 0; i < 16; ++i) sm += __expf(x[i] - mx);
#pragma unroll
            for (int o = 1; o < 64; o <<= 1) sm += __shfl_xor(sm, o);
            if (l == 0) { rowstat[row][0] = mx; rowstat[row][1] = 1.0f / sm; }
        }
        __syncthreads();

        {
            const int row = t >> 4, ci = t & 15;
            const float mx  = rowstat[row][0];
            const float inv = rowstat[row][1];
            const float fac = p ? -lam : 1.0f;
            float* aout = (p ? out_a2 : out_a1) + ((size_t)bh * S_LEN + q0 + row) * S_LEN;
            const float* Crow = Cm + (size_t)(q0 + row) * S_LEN;
#pragma unroll
            for (int it = 0; it < 8; ++it) {
                const int c0 = ci * 8 + it * 128;
                u16x8 sv = *(const u16x8*)&sc[row][c0];
                float4 Ca = *(const float4*)&Crow[c0];
                float4 Cb = *(const float4*)&Crow[c0 + 4];
                float e[8];
#pragma unroll
                for (int i = 0; i < 8; ++i) e[i] = __expf(h2f(sv[i]) - mx) * inv;
                float4 oa = {e[0], e[1], e[2], e[3]};
                float4 ob = {e[4], e[5], e[6], e[7]};
                *(float4*)&aout[c0]     = oa;
                *(float4*)&aout[c0 + 4] = ob;
                u16x8 cw;
                cw[0] = f2bf(Ca.x * e[0] * fac);
                cw[1] = f2bf(Ca.y * e[1] * fac);
                cw[2] = f2bf(Ca.z * e[2] * fac);
                cw[3] = f2bf(Ca.w * e[3] * fac);
                cw[4] = f2bf(Cb.x * e[4] * fac);
                cw[5] = f2bf(Cb.y * e[5] * fac);
                cw[6] = f2bf(Cb.z * e[6] * fac);
                cw[7] = f2bf(Cb.w * e[7] * fac);
                *(u16x8*)&sc[row][c0] = cw;
            }
        }
        __syncthreads();

        {
            const unsigned short* vtb = vt + (size_t)bh * 65536
                                           + (size_t)(dt * 16 + ln) * S_LEN + kf;
#pragma unroll 4
            for (int ks = khf; ks < khf + 16; ++ks) {
                bf16x8 A0 = *(const bf16x8*)&sc[ln][ks * 32 + kf];
                bf16x8 A1 = *(const bf16x8*)&sc[16 + ln][ks * 32 + kf];
                bf16x8 Bv = *(const bf16x8*)(vtb + ks * 32);
                c40 = MFMA(A0, Bv, c40);
                c41 = MFMA(A1, Bv, c41);
            }
        }
    }

    __syncthreads();
    float* red = (float*)&sc[0][0];
    if ((w >> 2) == 1) {
        *(f32x4*)&red[((dt * 2 + 0) * 64 + l) * 4] = c40;
        *(f32x4*)&red[((dt * 2 + 1) * 64 + l) * 4] = c41;
    }
    __syncthreads();
    if ((w >> 2) == 0) {
        f32x4 r0 = *(const f32x4*)&red[((dt * 2 + 0) * 64 + l) * 4];
        f32x4 r1 = *(const f32x4*)&red[((dt * 2 + 1) * 64 + l) * 4];
        c40 += r0;
        c41 += r1;
        const int col = h * DH + dt * 16 + ln;
#pragma unroll
        for (int r = 0; r < 4; ++r) {
            merged[(size_t)(b * S_LEN + q0 + (l >> 4) * 4 + r) * 1024 + col]      = c40[r];
            merged[(size_t)(b * S_LEN + q0 + 16 + (l >> 4) * 4 + r) * 1024 + col] = c41[r];
        }
    }
}

// ======================= group-norm stats =======================
__global__ __launch_bounds__(256) void stats_kernel(
    const float* __restrict__ merged, float* __restrict__ stats)
{
    const int g = blockIdx.x;
    const int b = g >> 4, h = g & 15;
    const int t = threadIdx.x;
    float sum = 0.f, sq = 0.f;
    for (int i = t; i < 65536; i += 256) {
        const int s = i >> 6, d = i & 63;
        const float v = merged[((size_t)(b * S_LEN + s)) * 1024 + h * DH + d];
        sum += v; sq += v * v;
    }
#pragma unroll
    for (int off = 32; off > 0; off >>= 1) {
        sum += __shfl_xor(sum, off);
        sq  += __shfl_xor(sq, off);
    }
    __shared__ float rs[4], rq[4];
    const int wid = t >> 6;
    if ((t & 63) == 0) { rs[wid] = sum; rq[wid] = sq; }
    __syncthreads();
    if (t == 0) {
        const float S = rs[0] + rs[1] + rs[2] + rs[3];
        const float Q = rq[0] + rq[1] + rq[2] + rq[3];
        const float mean = S * (1.0f / 65536.0f);
        const float var  = Q * (1.0f / 65536.0f) - mean * mean;
        stats[2*g]   = mean;
        stats[2*g+1] = rsqrtf(var + 1e-5f);
    }
}

// ======================= groupnorm apply -> bf16 =======================
__global__ __launch_bounds__(256) void norm_conv_kernel(
    const float* __restrict__ merged, const float* __restrict__ stats,
    const float* __restrict__ gw, const float* __restrict__ gb,
    unsigned short* __restrict__ normed)
{
    const int idx = blockIdx.x * 256 + threadIdx.x;   // 524288
    const int m = idx >> 7;
    const int col8 = (idx & 127) * 8;
    const int b = m >> 10, h = col8 >> 6;
    const float mean = stats[2 * (b * 16 + h)];
    const float inv  = stats[2 * (b * 16 + h) + 1];
    float4 v0 = *(const float4*)&merged[(size_t)m * 1024 + col8];
    float4 v1 = *(const float4*)&merged[(size_t)m * 1024 + col8 + 4];
    float4 w0 = *(const float4*)&gw[col8];
    float4 w1 = *(const float4*)&gw[col8 + 4];
    float4 g0 = *(const float4*)&gb[col8];
    float4 g1 = *(const float4*)&gb[col8 + 4];
    float v[8] = {v0.x, v0.y, v0.z, v0.w, v1.x, v1.y, v1.z, v1.w};
    float wv[8] = {w0.x, w0.y, w0.z, w0.w, w1.x, w1.y, w1.z, w1.w};
    float gv[8] = {g0.x, g0.y, g0.z, g0.w, g1.x, g1.y, g1.z, g1.w};
    u16x8 o;
#pragma unroll
    for (int j = 0; j < 8; ++j)
        o[j] = f2bf(((v[j] - mean) * inv * wv[j] + gv[j]) * 0.2f);
    *(u16x8*)&normed[(size_t)m * 1024 + col8] = o;
}

// ======================= output GEMM (MFMA, single bf16) =======================
__global__ __launch_bounds__(256) void out_mfma_kernel(
    const unsigned short* __restrict__ An, const unsigned short* __restrict__ Wo_bf,
    const float* __restrict__ bo, float* __restrict__ out)
{
    __shared__ __align__(16) unsigned short As[128 * 64];
    __shared__ __align__(16) unsigned short Bs[128 * 64];

    const int t   = threadIdx.x;
    const int bid = blockIdx.x;                 // 256
    const int swz = (bid & 7) * 32 + (bid >> 3);
    const int n_idx = swz & 7, m_idx = swz >> 3;
    const int m0 = m_idx * 128, n0 = n_idx * 128;
    const int w = t >> 6, l = t & 63, ln = l & 15, kg = l >> 4;
    const int wm = w >> 1, wn = w & 1;

    f32x4 acc[4][4];
#pragma unroll
    for (int i = 0; i < 4; ++i)
#pragma unroll
        for (int j = 0; j < 4; ++j) acc[i][j] = (f32x4){0.f, 0.f, 0.f, 0.f};

    for (int k0 = 0; k0 < 1024; k0 += 64) {
        __syncthreads();
#pragma unroll
        for (int i = 0; i < 4; ++i) {
            const int e   = t + i * 256;
            const int row = e >> 3, cg = e & 7;
            const int off = (row * 128 + cg * 16) ^ ((row & 7) << 4);
            *(bf16x8*)((char*)As + off) = *(const bf16x8*)(An + (size_t)(m0 + row) * 1024 + k0 + cg * 8);
            *(bf16x8*)((char*)Bs + off) = *(const bf16x8*)(Wo_bf + (size_t)(n0 + row) * 1024 + k0 + cg * 8);
        }
        __syncthreads();
#pragma unroll
        for (int ks = 0; ks < 2; ++ks) {
            bf16x8 bfrag[4];
#pragma unroll
            for (int nj = 0; nj < 4; ++nj) {
                const int row = wn * 64 + nj * 16 + ln;
                const int off = (row * 128 + ks * 64 + kg * 16) ^ ((row & 7) << 4);
                bfrag[nj] = *(const bf16x8*)((const char*)Bs + off);
            }
#pragma unroll
            for (int mi = 0; mi < 4; ++mi) {
                const int row = wm * 64 + mi * 16 + ln;
                const int off = (row * 128 + ks * 64 + kg * 16) ^ ((row & 7) << 4);
                bf16x8 af = *(const bf16x8*)((const char*)As + off);
#pragma unroll
                for (int nj = 0; nj < 4; ++nj)
                    acc[mi][nj] = MFMA(af, bfrag[nj], acc[mi][nj]);
            }
        }
    }

#pragma unroll
    for (int mi = 0; mi < 4; ++mi) {
#pragma unroll
        for (int nj = 0; nj < 4; ++nj) {
            const int n = n0 + wn * 64 + nj * 16 + ln;
            const float bb = bo[n];
            const int mb = m0 + wm * 64 + mi * 16 + kg * 4;
#pragma unroll
            for (int r = 0; r < 4; ++r)
                out[(size_t)(mb + r) * 1024 + n] = acc[mi][nj][r] + bb;
        }
    }
}

// ======================= launcher =======================
extern "C" void kernel_launch(void* const* d_in, const int* in_sizes, int n_in,
                              void* d_out, int out_size, void* d_ws, size_t ws_size,
                              hipStream_t stream)
{
    const float* x   = (const float*)d_in[0];
    const float* lam = (const float*)d_in[1];
    const float* C   = (const float*)d_in[2];
    const int*   pad = (const int*)  d_in[3];
    const float* wq  = (const float*)d_in[4];
    const float* bq  = (const float*)d_in[5];
    const float* wk  = (const float*)d_in[6];
    const float* bk  = (const float*)d_in[7];
    const float* wv  = (const float*)d_in[8];
    const float* bv  = (const float*)d_in[9];
    const float* wo  = (const float*)d_in[10];
    const float* bo  = (const float*)d_in[11];
    const float* gw  = (const float*)d_in[12];
    const float* gb  = (const float*)d_in[13];

    float* out = (float*)d_out;
    float* a1  = out + 4194304;
    float* a2  = a1 + 67108864;

    float* ws = (float*)d_ws;
    // region A (HSZ floats): xh+xl, later reused as merged
    unsigned short* xh = (unsigned short*)ws;
    unsigned short* xl = xh + HSZ;
    float* merged = ws;                                   // alias (xh/xl dead after proj)
    // region B (4*HSZ floats): heads fp32 (q1,q2,k1,k2), later reused as normed
    float* heads = ws + HSZ;
    unsigned short* normed = (unsigned short*)heads;      // alias (heads dead after rope)
    // stats
    float* stats = heads + 4 * HSZ;                       // 128 floats
    // qk bf16 (8*HSZ), vt bf16 (HSZ), Wcat bf16 (6144*1024)
    unsigned short* qk   = (unsigned short*)(stats + 128);
    unsigned short* vt   = qk + 8 * HSZ;
    unsigned short* Wcat = vt + HSZ;

    conv_x_kernel<<<2048, 256, 0, stream>>>(x, xh, xl);
    conv_w_kernel<<<3072, 256, 0, stream>>>(wq, wk, wv, wo, Wcat);
    proj_mfma_kernel<<<1280, 256, 0, stream>>>(xh, xl, Wcat, bq, bk, bv, heads, vt);
    rope_conv_kernel<<<32768, 256, 0, stream>>>(heads, qk);
    attn_kernel<<<dim3(32, 64), 512, 0, stream>>>(qk, vt, C, pad, lam, a1, a2, merged);
    stats_kernel<<<64, 256, 0, stream>>>(merged, stats);
    norm_conv_kernel<<<2048, 256, 0, stream>>>(merged, stats, gw, gb, normed);
    out_mfma_kernel<<<256, 256, 0, stream>>>(normed, Wcat + 5120 * 1024, bo, out);
}